// Round 5
// baseline (228.743 us; speedup 1.0000x reference)
//
#include <hip/hip_runtime.h>

// GINE 2-layer GNN: N=50000 nodes, E=800000 edges, d=128.
// Round 17: two changes.
// (a) gine_layer gather loop on packed f32 (v_pk_fma/add/max_f32 via
//     f32x2 + __builtin_elementwise_*): ~halves the ~45 scalar VALU ops
//     per edge-lane that made VALUBusy=45% the co-bottleneck.
// (b) scan_bases: one-block kernel precomputes all NC*NB scatter bases
//     (reads 0.8 MB) replacing every scatter block's full-G read
//     (51 MB total) + 20-barrier LDS scan.
// Keep GR=32 grid (verified round 15/16), __launch_bounds__(256,4)
// (VGPR cap 128 -- the (256,6) 84-cap spilled). bf16 path, f32 accum.

typedef unsigned long long u64;
typedef unsigned int u32;
typedef unsigned short ushort;
typedef __attribute__((ext_vector_type(8))) short short8;
typedef __attribute__((ext_vector_type(4))) float f32x4;
typedef __attribute__((ext_vector_type(2))) float f32x2;
typedef __attribute__((ext_vector_type(4))) u32 u32x4;   // native vec for NT ops

constexpr int NN = 50000;
constexpr int NE = 800000;
constexpr int D  = 128;
constexpr int BSH = 6;                    // 64 nodes per bucket
constexpr int NB  = (NN + 63) >> BSH;     // 782 buckets
constexpr int NC  = 128;                  // edge chunks
constexpr int CHUNK = NE / NC;            // 6250
constexpr int BCAP = 4096;
constexpr int GR = 32;                    // GEMM rows per block
constexpr int GG = (NN + GR - 1) / GR;    // 1563
constexpr int CBLK = NN * D / 8 / 256;    // 3125 cast blocks (exact)

__device__ __forceinline__ ushort f2bf(float f) {
    u32 u = __float_as_uint(f);
    return (ushort)((u + 0x7FFFu + ((u >> 16) & 1u)) >> 16);
}
__device__ __forceinline__ float bfl(u32 u) {            // low bf16 -> f32
    return __uint_as_float(u << 16);
}
__device__ __forceinline__ float bfh(u32 u) {            // high bf16 -> f32
    return __uint_as_float(u & 0xFFFF0000u);
}
__device__ __forceinline__ f32x2 unpk(u32 u) {           // packed bf16 -> 2xf32
    f32x2 r; r.x = bfl(u); r.y = bfh(u); return r;
}
__device__ __forceinline__ u64 pack_edge(int src, int d6, float w) {
    return ((u64)__float_as_uint(w) << 32) | (u32)(src | (d6 << 17));
}

// ---- prep+hist: cast x -> bf16, transpose+cast W1/W2, dst histogram ----

__global__ __launch_bounds__(256) void prep_hist(
    const float* __restrict__ x,  ushort* __restrict__ xb,
    const float* __restrict__ W1, const float* __restrict__ W2,
    ushort* __restrict__ Wt1, ushort* __restrict__ Wt2,
    const int* __restrict__ dst, int* __restrict__ G)
{
    int blk = blockIdx.x;
    if (blk < CBLK) {
        int base = (blk * 256 + threadIdx.x) * 8;
        float4 a = *(const float4*)(x + base);
        float4 b = *(const float4*)(x + base + 4);
        uint4 o;
        o.x = (u32)f2bf(a.x) | ((u32)f2bf(a.y) << 16);
        o.y = (u32)f2bf(a.z) | ((u32)f2bf(a.w) << 16);
        o.z = (u32)f2bf(b.x) | ((u32)f2bf(b.y) << 16);
        o.w = (u32)f2bf(b.z) | ((u32)f2bf(b.w) << 16);
        *(uint4*)(xb + base) = o;
    } else if (blk < CBLK + 8) {
        int b = blk - CBLK;                 // 0..7
        const float* W  = (b >= 4) ? W2 : W1;
        ushort*      Wt = (b >= 4) ? Wt2 : Wt1;
        int k0 = (b & 3) * 32;
        for (int i = threadIdx.x; i < 32 * D; i += 256) {
            int n = i >> 5, r = i & 31;
            Wt[n * D + k0 + r] = f2bf(W[(k0 + r) * D + n]);
        }
    } else {
        __shared__ int hh[NB];
        int t = threadIdx.x, c = blk - CBLK - 8;
        for (int i = t; i < NB; i += 256) hh[i] = 0;
        __syncthreads();
        int e0 = c * CHUNK;
        for (int i = t; i < CHUNK; i += 256)
            atomicAdd(&hh[dst[e0 + i] >> BSH], 1);
        __syncthreads();
        for (int i = t; i < NB; i += 256) G[c * NB + i] = hh[i];
    }
}

// ---- scan_bases: one block; per-(chunk,bucket) scatter bases + B ----

__global__ __launch_bounds__(1024) void scan_bases(
    const int* __restrict__ G, int* __restrict__ P, int* __restrict__ B)
{
    __shared__ int tsum[1024];
    int t = threadIdx.x;
    int S = 0;
    if (t < NB) {
        #pragma unroll 4
        for (int cc = 0; cc < NC; ++cc) S += G[cc * NB + t];
    }
    tsum[t] = S;
    __syncthreads();
    for (int d = 1; d < 1024; d <<= 1) {
        int v = (t >= d) ? tsum[t - d] : 0;
        __syncthreads();
        tsum[t] += v;
        __syncthreads();
    }
    if (t < NB) {
        int run = tsum[t] - S;             // exclusive bucket base
        B[t] = run;
        #pragma unroll 4
        for (int cc = 0; cc < NC; ++cc) {
            P[cc * NB + t] = run;
            run += G[cc * NB + t];
        }
    }
    if (t == 0) B[NB] = NE;
}

// ---- bucket_scatter: pure scatter, bases precomputed ----

__global__ __launch_bounds__(1024) void bucket_scatter(
    const int*   __restrict__ src,
    const int*   __restrict__ dst,
    const float* __restrict__ ew,
    const int*   __restrict__ P,
    u64*         __restrict__ stage)
{
    __shared__ int base_s[NB];
    __shared__ int cnt_s[NB];
    const int t = threadIdx.x, c = blockIdx.x;
    for (int i = t; i < NB; i += 1024) {
        base_s[i] = P[c * NB + i];
        cnt_s[i] = 0;
    }
    __syncthreads();
    int e0 = c * CHUNK;
    for (int i = t; i < CHUNK; i += 1024) {
        int e  = e0 + i;
        int d  = dst[e];
        int bk = d >> BSH;
        int r  = atomicAdd(&cnt_s[bk], 1);
        stage[base_s[bk] + r] = pack_edge(src[e], d & 63, ew[e]);
    }
}

// per bucket: counting sort by node, contiguous writeback, per-node offsets.
__global__ __launch_bounds__(256) void bucket_csr(
    const int* __restrict__ B, u64* __restrict__ stage, int* __restrict__ off)
{
    __shared__ u64 buf[BCAP];           // 32 KB
    __shared__ int cnt[64];
    __shared__ int cur[64];
    __shared__ int noff[64];
    int t = threadIdx.x, b = blockIdx.x;
    int e0 = B[b], e1 = B[b + 1];
    int n = e1 - e0;
    if (n > BCAP) n = BCAP;
    if (t < 64) { cnt[t] = 0; cur[t] = 0; }
    __syncthreads();
    for (int i = t; i < n; i += 256)
        atomicAdd(&cnt[(int)((stage[e0 + i] >> 17) & 63)], 1);
    __syncthreads();
    if (t == 0) {
        int run = 0;
        for (int j = 0; j < 64; ++j) { noff[j] = run; run += cnt[j]; }
    }
    __syncthreads();
    int n0 = b << BSH;
    if (t < 64 && (n0 + t) < NN) off[n0 + t] = e0 + noff[t];
    if (b == NB - 1 && t == 0) off[NN] = NE;
    for (int i = t; i < n; i += 256) {
        u64 p = stage[e0 + i];
        int d6 = (int)((p >> 17) & 63);
        int r = atomicAdd(&cur[d6], 1);
        buf[noff[d6] + r] = p;
    }
    __syncthreads();
    for (int i = t; i < n; i += 256) stage[e0 + i] = buf[i];
}

// ---- fused layer: aggregate (gather, packed f32 acc) + self + MFMA gemm --
// out = (relu?)((h + sum_{e->n} relu(h[src_e] + w_e*We + be)) @ W + bias)

__global__ __launch_bounds__(256, 4) void gine_layer(
    const ushort* __restrict__ hb,     // input features bf16 [NN][D]
    const int*    __restrict__ off,    // CSR offsets into sorted stage
    const u64*    __restrict__ epk,    // sorted packed edges
    const float*  __restrict__ We,
    const float*  __restrict__ be,
    const ushort* __restrict__ Wtb,    // transposed weight bf16 [D][D]
    const float*  __restrict__ bias,
    float*        __restrict__ outf,   // layer 2 (or null)
    ushort*       __restrict__ outb,   // layer 1 (or null)
    int relu)
{
    __shared__ ushort As[GR * 140];    // 9 KB -- only LDS in the kernel

    const int t    = threadIdx.x;
    const int row0 = blockIdx.x * GR;

    // ---- phase 1: aggregate edges + self term -> As (bf16) ----
    // 16 lanes per node, 8 features per lane (4x f32x2), 8-deep edge
    // unroll, one-iteration-ahead prefetch of the packed-edge words.
    const int g  = t >> 4;             // node group 0..15
    const int d8 = (t & 15) << 3;

    f32x2 wv[4], bv[4];
    #pragma unroll
    for (int j = 0; j < 4; ++j) {
        wv[j] = *(const f32x2*)(We + d8 + 2 * j);
        bv[j] = *(const f32x2*)(be + d8 + 2 * j);
    }
    const f32x2 zero2 = {0.f, 0.f};

    for (int nrep = 0; nrep < GR / 16; ++nrep) {
        int ln = nrep * 16 + g;        // local row 0..GR-1
        int n  = row0 + ln;
        f32x2 a[4] = {zero2, zero2, zero2, zero2};
        if (n < NN) {
            // self term: issue early, consume after the edge loop
            u32x4 sv = *(const u32x4*)(hb + (size_t)n * D + d8);
            int e0 = off[n], e1 = off[n + 1];
            u64 p[8];
            int m0 = e1 - e0; if (m0 > 8) m0 = 8;
            #pragma unroll
            for (int k = 0; k < 8; ++k) p[k] = (k < m0) ? epk[e0 + k] : 0;
            for (int e = e0; e < e1; e += 8) {
                int m = e1 - e; if (m > 8) m = 8;
                u32x4 hv[8];
                #pragma unroll
                for (int k = 0; k < 8; ++k)
                    hv[k] = *(const u32x4*)(hb + (size_t)(p[k] & 0x1FFFF) * D + d8);
                // prefetch next iteration's packed edges under the hv wait
                u64 pn[8];
                int mn = e1 - (e + 8); if (mn > 8) mn = 8;
                #pragma unroll
                for (int k = 0; k < 8; ++k)
                    pn[k] = (k < mn) ? epk[e + 8 + k] : 0;
                #pragma unroll
                for (int k = 0; k < 8; ++k) {
                    if (k < m) {
                        float w = __uint_as_float((u32)(p[k] >> 32));
                        f32x2 w2 = {w, w};
                        a[0] += __builtin_elementwise_max(zero2,
                                  unpk(hv[k].x) + __builtin_elementwise_fma(w2, wv[0], bv[0]));
                        a[1] += __builtin_elementwise_max(zero2,
                                  unpk(hv[k].y) + __builtin_elementwise_fma(w2, wv[1], bv[1]));
                        a[2] += __builtin_elementwise_max(zero2,
                                  unpk(hv[k].z) + __builtin_elementwise_fma(w2, wv[2], bv[2]));
                        a[3] += __builtin_elementwise_max(zero2,
                                  unpk(hv[k].w) + __builtin_elementwise_fma(w2, wv[3], bv[3]));
                    }
                }
                #pragma unroll
                for (int k = 0; k < 8; ++k) p[k] = pn[k];
            }
            // self term (h_n), f32 add before the single bf16 rounding
            a[0] += unpk(sv.x);
            a[1] += unpk(sv.y);
            a[2] += unpk(sv.z);
            a[3] += unpk(sv.w);
        }
        uint2 lo, hi;
        lo.x = (u32)f2bf(a[0].x) | ((u32)f2bf(a[0].y) << 16);
        lo.y = (u32)f2bf(a[1].x) | ((u32)f2bf(a[1].y) << 16);
        hi.x = (u32)f2bf(a[2].x) | ((u32)f2bf(a[2].y) << 16);
        hi.y = (u32)f2bf(a[3].x) | ((u32)f2bf(a[3].y) << 16);
        *(uint2*)&As[ln * 140 + d8]     = lo;
        *(uint2*)&As[ln * 140 + d8 + 4] = hi;
    }
    __syncthreads();

    // ---- phase 2: MFMA gemm, 32x128 output; B-fragments straight from
    // global (L2-resident 32 KB, shared by all blocks; MFMA ~1% of time) ----
    const int wave = t >> 6;           // 0..3 -> 32-col slab
    const int lane = t & 63;
    const int q    = lane >> 4;
    const int m    = lane & 15;
    const int wc   = wave * 32;

    f32x4 acc[2][2] = {};
    #pragma unroll
    for (int kb = 0; kb < 4; ++kb) {
        int ak = kb * 32 + q * 8;
        short8 af[2];
        #pragma unroll
        for (int rg = 0; rg < 2; ++rg)
            af[rg] = *(const short8*)&As[(rg * 16 + m) * 140 + ak];
        #pragma unroll
        for (int ct = 0; ct < 2; ++ct) {
            short8 bf = *(const short8*)(Wtb + (wc + ct * 16 + m) * D + ak);
            #pragma unroll
            for (int rg = 0; rg < 2; ++rg)
                acc[rg][ct] = __builtin_amdgcn_mfma_f32_16x16x32_bf16(
                    af[rg], bf, acc[rg][ct], 0, 0, 0);
        }
    }

    #pragma unroll
    for (int ct = 0; ct < 2; ++ct) {
        int col = wc + ct * 16 + m;
        float bc = bias[col];
        #pragma unroll
        for (int rg = 0; rg < 2; ++rg) {
            #pragma unroll
            for (int r = 0; r < 4; ++r) {
                int grow = row0 + rg * 16 + q * 4 + r;
                if (grow < NN) {
                    float v = acc[rg][ct][r] + bc;
                    if (relu) v = fmaxf(0.f, v);
                    if (outb) outb[(size_t)grow * D + col] = f2bf(v);
                    else __builtin_nontemporal_store(v, outf + (size_t)grow * D + col);
                }
            }
        }
    }
}

extern "C" void kernel_launch(void* const* d_in, const int* in_sizes, int n_in,
                              void* d_out, int out_size, void* d_ws, size_t ws_size,
                              hipStream_t stream)
{
    const float* x   = (const float*)d_in[0];
    const int*   ei  = (const int*)  d_in[1];
    const float* ew  = (const float*)d_in[2];
    const float* We1 = (const float*)d_in[3];
    const float* be1 = (const float*)d_in[4];
    const float* W1  = (const float*)d_in[5];
    const float* b1  = (const float*)d_in[6];
    const float* We2 = (const float*)d_in[7];
    const float* be2 = (const float*)d_in[8];
    const float* W2  = (const float*)d_in[9];
    const float* b2  = (const float*)d_in[10];

    float* out = (float*)d_out;

    // workspace (~47 MB)
    ushort* xb   = (ushort*)d_ws;                    // NN*D bf16
    ushort* hb   = xb + (size_t)NN * D;              // NN*D
    ushort* aggb = hb + (size_t)NN * D;              // NN*D (unused)
    ushort* Wt1  = aggb + (size_t)NN * D;            // 16384
    ushort* Wt2  = Wt1 + D * D;                      // 16384
    u64*   stage = (u64*)(Wt2 + D * D);              // NE u64
    int*   G     = (int*)(stage + NE);               // NC*NB
    int*   P     = G + NC * NB;                      // NC*NB (scatter bases)
    int*   B     = P + NC * NB;                      // NB+1
    int*   off   = B + NB + 2;                       // NN+1

    const int* src = ei;
    const int* dst = ei + NE;

    // ---- prep (cast x, transpose W) + hist, one launch ----
    prep_hist<<<CBLK + 8 + NC, 256, 0, stream>>>(x, xb, W1, W2, Wt1, Wt2,
                                                 dst, G);

    // ---- bucket-sorted CSR build ----
    scan_bases<<<1, 1024, 0, stream>>>(G, P, B);
    bucket_scatter<<<NC, 1024, 0, stream>>>(src, dst, ew, P, stage);
    bucket_csr<<<NB, 256, 0, stream>>>(B, stage, off);

    // ---- layer 1 (fused aggregate + gemm) ----
    gine_layer<<<GG, 256, 0, stream>>>(xb, off, stage, We1, be1, Wt1, b1,
                                       nullptr, hb, 1);

    // ---- layer 2 (fused aggregate + gemm) ----
    gine_layer<<<GG, 256, 0, stream>>>(hb, off, stage, We2, be2, Wt2, b2,
                                       out, nullptr, 0);
}